// Round 7
// baseline (156.705 us; speedup 1.0000x reference)
//
#include <hip/hip_runtime.h>
#include <math.h>

#define HIDDEN 64
#define RANGE 16384       // nodes per LDS bin range (64 KB f32 bins), 2^14
#define RSHIFT 14
#define G 32              // chunks per range in binning passes (224 blocks total)
#define NB 256            // compaction blocks
#define MAXR 8            // max ranges (N <= 131072 -> src fits 17 bits)
#define PACK_SHIFT 17

// ---------------------------------------------------------------------------
// Bucket-sort edges by dst-range in ONE read of the edge list.
// Per block: LDS histogram of its chunk (1 LDS atomic/edge), bulk-reserve
// space in each range bucket (7 global atomicAdds per block TOTAL — per-edge
// global atomics were the R1 disaster), then emit (pack,ew) uint2 records,
// re-reading the chunk from L2 (75 KB/block -> L2-hot).
// Bucket r lives at comp + r*capE (capE = E: overflow-impossible).
// After this kernel gcur[r] = bucket r's edge count.
// ---------------------------------------------------------------------------
__global__ __launch_bounds__(256)
void k_compact(const int* __restrict__ dst, const int* __restrict__ src,
               const float* __restrict__ ew, uint2* __restrict__ comp,
               int* __restrict__ gcur, int E, int capE) {
    __shared__ int hist[MAXR];
    __shared__ int rbase[MAXR];
    __shared__ int cur[MAXR];
    if (threadIdx.x < MAXR) hist[threadIdx.x] = 0;
    __syncthreads();

    long long e0 = (((long long)E * blockIdx.x) / NB) & ~3LL;
    long long e1 = (blockIdx.x == NB - 1) ? (long long)E
                                          : ((((long long)E * (blockIdx.x + 1)) / NB) & ~3LL);
    const int nvec = (int)((e1 - e0) >> 2);
    const int4*   dst4 = (const int4*)(dst + e0);
    const int4*   src4 = (const int4*)(src + e0);
    const float4* ew4  = (const float4*)(ew + e0);

    // Phase 1: count
    for (int i = threadIdx.x; i < nvec; i += blockDim.x) {
        int4 d = dst4[i];
        atomicAdd(&hist[d.x >> RSHIFT], 1);
        atomicAdd(&hist[d.y >> RSHIFT], 1);
        atomicAdd(&hist[d.z >> RSHIFT], 1);
        atomicAdd(&hist[d.w >> RSHIFT], 1);
    }
    for (long long e = e0 + ((long long)nvec << 2) + threadIdx.x; e < e1; e += blockDim.x)
        atomicAdd(&hist[dst[e] >> RSHIFT], 1);
    __syncthreads();

    // Bulk reservation (device-scope atomic, but only MAXR per block)
    if (threadIdx.x < MAXR) {
        rbase[threadIdx.x] = atomicAdd(&gcur[threadIdx.x], hist[threadIdx.x]);
        cur[threadIdx.x] = 0;
    }
    __syncthreads();

    // Phase 2: emit (chunk re-read is L2-hot)
    for (int i = threadIdx.x; i < nvec; i += blockDim.x) {
        int4   d = dst4[i];
        int4   s = src4[i];
        float4 t = ew4[i];
        int   dd[4] = {d.x, d.y, d.z, d.w};
        int   ss[4] = {s.x, s.y, s.z, s.w};
        float tt[4] = {t.x, t.y, t.z, t.w};
        #pragma unroll
        for (int j = 0; j < 4; ++j) {
            int r = dd[j] >> RSHIFT;
            int pos = atomicAdd(&cur[r], 1);
            comp[(size_t)r * capE + rbase[r] + pos] =
                make_uint2(((unsigned)(dd[j] & (RANGE - 1)) << PACK_SHIFT) | (unsigned)ss[j],
                           __float_as_uint(tt[j]));
        }
    }
    for (long long e = e0 + ((long long)nvec << 2) + threadIdx.x; e < e1; e += blockDim.x) {
        int d = dst[e];
        int r = d >> RSHIFT;
        int pos = atomicAdd(&cur[r], 1);
        comp[(size_t)r * capE + rbase[r] + pos] =
            make_uint2(((unsigned)(d & (RANGE - 1)) << PACK_SHIFT) | (unsigned)src[e],
                       __float_as_uint(ew[e]));
    }
}

// ---------------------------------------------------------------------------
// Binning over compacted buckets: lean loop — 8 B read + 1 ds_add per edge.
// WEIGHTED=false: bin ew (degree). WEIGHTED=true: bin w[src]*ew (aggregate).
// Grid = nranges*G, blockIdx = r*G + c; flush to private partials[c][r].
// ---------------------------------------------------------------------------
template <bool WEIGHTED>
__global__ __launch_bounds__(1024)
void k_bin(const uint2* __restrict__ comp, const int* __restrict__ gcur,
           const float* __restrict__ w, float* __restrict__ partials,
           int nranges, int capE) {
    __shared__ float bins[RANGE];
    float4* b4 = (float4*)bins;
    for (int i = threadIdx.x; i < RANGE / 4; i += blockDim.x)
        b4[i] = make_float4(0.f, 0.f, 0.f, 0.f);
    __syncthreads();

    const int r = blockIdx.x / G, c = blockIdx.x % G;
    const int len = gcur[r];
    const uint2* bucket = comp + (size_t)r * capE;
    const int a0 = (int)((long long)len * c / G);
    const int a1 = (int)((long long)len * (c + 1) / G);

    for (int i = a0 + threadIdx.x; i < a1; i += blockDim.x) {
        uint2 e = bucket[i];
        float v = __uint_as_float(e.y);
        if (WEIGHTED) v *= w[e.x & ((1u << PACK_SHIFT) - 1u)];
        atomicAdd(&bins[e.x >> PACK_SHIFT], v);   // ds_add_f32
    }
    __syncthreads();

    float4* outp = (float4*)(partials + ((size_t)c * nranges + r) * RANGE);
    for (int i = threadIdx.x; i < RANGE / 4; i += blockDim.x) outp[i] = b4[i];
}

// ---------------------------------------------------------------------------
// Reduce deg partials -> dinv = rsqrt(deg+1), w = dinv*x.
// Block 0 also computes fused GRU coefficients (H0=0 => only top 64 rows of
// Lz/Lh matter; the R gate is dead code).
// ---------------------------------------------------------------------------
__global__ void k_node(const float* __restrict__ x, const float* __restrict__ partials,
                       float* __restrict__ dinv, float* __restrict__ w,
                       int N, int nranges,
                       const float* __restrict__ Wz, const float* __restrict__ bz,
                       const float* __restrict__ Lz, const float* __restrict__ lbz,
                       const float* __restrict__ Wh, const float* __restrict__ bh,
                       const float* __restrict__ Lh, const float* __restrict__ lbh,
                       float* __restrict__ coeff) {
    int i = blockIdx.x * blockDim.x + threadIdx.x;
    if (i < N) {
        int r = i >> RSHIFT, local = i & (RANGE - 1);
        const float* p = partials + (size_t)r * RANGE + local;
        float d = 1.0f;   // self-loop
        #pragma unroll
        for (int c = 0; c < G; ++c) d += p[(size_t)c * nranges * RANGE];
        float di = rsqrtf(d);
        dinv[i] = di;
        w[i] = di * x[i];
    }
    if (blockIdx.x == 0 && threadIdx.x < HIDDEN) {
        int j = threadIdx.x;
        float vz = 0.f, cz = 0.f, vh = 0.f, ch = 0.f;
        for (int k = 0; k < HIDDEN; ++k) {
            float lz = Lz[k * HIDDEN + j];
            float lh = Lh[k * HIDDEN + j];
            vz += Wz[k] * lz;
            cz += bz[k] * lz;
            vh += Wh[k] * lh;
            ch += bh[k] * lh;
        }
        coeff[j]       = vz;
        coeff[64 + j]  = cz + lbz[j];
        coeff[128 + j] = vh;
        coeff[192 + j] = ch + lbh[j];
    }
}

// ---------------------------------------------------------------------------
// Reduce agg partials, add self-loop, fused GRU + output head:
//   s = dinv*(sum_c P[c][i] + w[i]),
//   out[i] = sum_j relu(sigmoid(-zp)*tanh(hp)) * Wout_j + bout.
// ---------------------------------------------------------------------------
__global__ void k_out(const float* __restrict__ partials, const float* __restrict__ dinv,
                      const float* __restrict__ w, const float* __restrict__ coeff,
                      const float* __restrict__ Wout, const float* __restrict__ bout,
                      float* __restrict__ out, int N, int nranges) {
    __shared__ float c[5 * HIDDEN];
    __shared__ float b0;
    if (threadIdx.x < 4 * HIDDEN) c[threadIdx.x] = coeff[threadIdx.x];
    if (threadIdx.x < HIDDEN) c[4 * HIDDEN + threadIdx.x] = Wout[threadIdx.x];
    if (threadIdx.x == 0) b0 = bout[0];
    __syncthreads();
    int i = blockIdx.x * blockDim.x + threadIdx.x;
    if (i < N) {
        int r = i >> RSHIFT, local = i & (RANGE - 1);
        const float* p = partials + (size_t)r * RANGE + local;
        float g = w[i];
        #pragma unroll
        for (int k = 0; k < G; ++k) g += p[(size_t)k * nranges * RANGE];
        float si = dinv[i] * g;
        float acc = b0;
        #pragma unroll
        for (int j = 0; j < HIDDEN; ++j) {
            float zp = fminf(fmaxf(si * c[j] + c[64 + j], -30.f), 30.f);
            float hp = fminf(fmaxf(si * c[128 + j] + c[192 + j], -15.f), 15.f);
            float a  = __expf(2.0f * hp);               // tanh(hp)=(a-1)/(a+1)
            float t  = (a - 1.0f) / (a + 1.0f);
            float zn = 1.0f / (1.0f + __expf(zp));      // 1 - sigmoid(zp)
            float hn = zn * t;
            hn = hn > 0.0f ? hn : 0.0f;
            acc = fmaf(hn, c[256 + j], acc);
        }
        out[i] = acc;
    }
}

extern "C" void kernel_launch(void* const* d_in, const int* in_sizes, int n_in,
                              void* d_out, int out_size, void* d_ws, size_t ws_size,
                              hipStream_t stream) {
    const float* x    = (const float*)d_in[0];
    const float* ew   = (const float*)d_in[1];
    const float* Wz   = (const float*)d_in[2];
    const float* bz   = (const float*)d_in[3];
    const float* Lz   = (const float*)d_in[4];
    const float* lbz  = (const float*)d_in[5];
    // d_in[6..9] = Wr, br, Lr, lbr — dead (H0 = 0 makes the R gate unused)
    const float* Wh   = (const float*)d_in[10];
    const float* bh   = (const float*)d_in[11];
    const float* Lh   = (const float*)d_in[12];
    const float* lbh  = (const float*)d_in[13];
    const float* Wout = (const float*)d_in[14];
    const float* bout = (const float*)d_in[15];
    const int*   eidx = (const int*)d_in[16];

    const int N = in_sizes[0];          // x is [N,1]  (100000 -> src fits 17 bits)
    const int E = in_sizes[1];          // edge_weight is [E]
    const int* src = eidx;              // edge_index[0]
    const int* dst = eidx + E;          // edge_index[1]

    const int nranges = (N + RANGE - 1) / RANGE;   // 7
    const int capE = E;                 // per-bucket capacity: provably sufficient

    // Workspace (~105 MB of the 256 MiB d_ws):
    float* partials = (float*)d_ws;                                     // G*nranges*RANGE
    uint2* comp     = (uint2*)(partials + (size_t)G * nranges * RANGE); // nranges*capE
    float* dinv     = (float*)(comp + (size_t)nranges * capE);          // N
    float* w        = dinv + N;                                         // N
    float* coeff    = w + N;                                            // 4*HIDDEN
    int*   gcur     = (int*)(coeff + 4 * HIDDEN);                       // MAXR

    const int TB = 256;
    const int grid_bin = nranges * G;   // 224 blocks, 64 KB LDS each

    hipMemsetAsync(gcur, 0, MAXR * sizeof(int), stream);
    // Bucket sort by dst-range: one edge-list read, bulk-reserved emission
    k_compact<<<NB, 256, 0, stream>>>(dst, src, ew, comp, gcur, E, capE);
    // Deg binning over compacted buckets
    k_bin<false><<<grid_bin, 1024, 0, stream>>>(comp, gcur, (const float*)nullptr,
                                                partials, nranges, capE);
    // deg -> dinv, w = dinv*x; plus GRU coefficient fusion
    k_node<<<(N + TB - 1) / TB, TB, 0, stream>>>(x, partials, dinv, w, N, nranges,
                                                 Wz, bz, Lz, lbz, Wh, bh, Lh, lbh, coeff);
    // Aggregation binning (w[src]*ew) over the same compacted buckets (L2-warm)
    k_bin<true><<<grid_bin, 1024, 0, stream>>>(comp, gcur, w, partials, nranges, capE);
    // Reduce + fused GRU + output head
    k_out<<<(N + TB - 1) / TB, TB, 0, stream>>>(partials, dinv, w, coeff, Wout, bout,
                                                (float*)d_out, N, nranges);
}